// Round 1
// baseline (179.033 us; speedup 1.0000x reference)
//
#include <hip/hip_runtime.h>
#include <hip/hip_bf16.h>

#define NN 100000   // nodes
#define KN 32       // neighbors per node
#define DD 128      // D_IN == D_OUT

typedef __attribute__((ext_vector_type(8))) short bf16x8;
typedef __attribute__((ext_vector_type(4))) float f32x4;

// f32 -> bf16 bits, round-to-nearest-even (inputs are finite; no NaN handling)
__device__ __forceinline__ unsigned short f2bf(float x) {
  unsigned int u = __float_as_uint(x);
  u += 0x7fffu + ((u >> 16) & 1u);
  return (unsigned short)(u >> 16);
}

// Kernel 1: h = relu(F @ W^T + b), bf16 output into workspace.
// Grid: 6250 blocks x 256 threads. Block = 16 rows x 128 cols.
// Wave w owns cols [w*32, w*32+32): two 16-col n-tiles. B (= W^T) fragments
// live in registers for the whole kernel; no LDS, no barriers.
// MFMA 16x16x32 bf16. Fragment layout (guide §3):
//   A: lane l holds A[l&15][kt*32 + (l>>4)*8 + i], i=0..7 (contiguous k)
//   B: lane l holds B[kt*32 + (l>>4)*8 + i][l&15] = W[l&15-col][k...] contiguous
//   C/D: col = l&15, row = (l>>4)*4 + reg   [m89-verified]
__global__ __launch_bounds__(256) void k_transform(
    const float* __restrict__ F, const float* __restrict__ W,
    const float* __restrict__ bias, unsigned short* __restrict__ h) {
  const int lane = (int)(threadIdx.x & 63);
  const int wid  = (int)(threadIdx.x >> 6);  // 0..3
  const int lr = lane & 15;
  const int lk = (lane >> 4) * 8;
  const int n0 = wid * 32;

  // Preload B fragments (W rows are h's columns; contiguous in k). 32 VGPRs.
  bf16x8 bfrag[2][4];
#pragma unroll
  for (int nt = 0; nt < 2; ++nt) {
    const float* wsrc = W + (size_t)(n0 + nt * 16 + lr) * DD;
#pragma unroll
    for (int kt = 0; kt < 4; ++kt) {
      float4 w0 = *(const float4*)(wsrc + kt * 32 + lk);
      float4 w1 = *(const float4*)(wsrc + kt * 32 + lk + 4);
      bf16x8 t;
      t[0] = (short)f2bf(w0.x); t[1] = (short)f2bf(w0.y);
      t[2] = (short)f2bf(w0.z); t[3] = (short)f2bf(w0.w);
      t[4] = (short)f2bf(w1.x); t[5] = (short)f2bf(w1.y);
      t[6] = (short)f2bf(w1.z); t[7] = (short)f2bf(w1.w);
      bfrag[nt][kt] = t;
    }
  }
  const float bias0 = bias[n0 + lr];
  const float bias1 = bias[n0 + 16 + lr];

  const int r0 = (int)blockIdx.x * 16;  // 6250 * 16 = 100000 exactly

  // A fragments for this 16-row tile (all 4 waves read the same 8KB; L1 hit)
  const float* fsrc = F + (size_t)(r0 + lr) * DD + lk;
  bf16x8 afrag[4];
#pragma unroll
  for (int kt = 0; kt < 4; ++kt) {
    float4 a0 = *(const float4*)(fsrc + kt * 32);
    float4 a1 = *(const float4*)(fsrc + kt * 32 + 4);
    bf16x8 t;
    t[0] = (short)f2bf(a0.x); t[1] = (short)f2bf(a0.y);
    t[2] = (short)f2bf(a0.z); t[3] = (short)f2bf(a0.w);
    t[4] = (short)f2bf(a1.x); t[5] = (short)f2bf(a1.y);
    t[6] = (short)f2bf(a1.z); t[7] = (short)f2bf(a1.w);
    afrag[kt] = t;
  }

  f32x4 acc0 = {0.f, 0.f, 0.f, 0.f};
  f32x4 acc1 = {0.f, 0.f, 0.f, 0.f};
#pragma unroll
  for (int kt = 0; kt < 4; ++kt) {
    acc0 = __builtin_amdgcn_mfma_f32_16x16x32_bf16(afrag[kt], bfrag[0][kt], acc0, 0, 0, 0);
    acc1 = __builtin_amdgcn_mfma_f32_16x16x32_bf16(afrag[kt], bfrag[1][kt], acc1, 0, 0, 0);
  }

  // Epilogue: +bias, ReLU, bf16, store.
#pragma unroll
  for (int j = 0; j < 4; ++j) {
    const int row = r0 + (lane >> 4) * 4 + j;
    h[(size_t)row * DD + n0 + lr]      = f2bf(fmaxf(acc0[j] + bias0, 0.f));
    h[(size_t)row * DD + n0 + 16 + lr] = f2bf(fmaxf(acc1[j] + bias1, 0.f));
  }
}

// Kernel 2: out[i][d] = max_j h[nbr[i][j]][d]. One wave per node.
// Each neighbor row = 256B bf16 = 64 lanes x 4B -> one coalesced wave read.
// h >= 0 (ReLU), so f32 max init 0 is exact.
__global__ __launch_bounds__(256) void k_gather(
    const int* __restrict__ nbr, const unsigned int* __restrict__ h,
    float* __restrict__ out) {
  const int lane = (int)(threadIdx.x & 63);
  const int node = (int)blockIdx.x * 4 + (int)(threadIdx.x >> 6);  // 25000*4 = 100000

  const int nv = nbr[(size_t)node * KN + (lane & 31)];
  float m0 = 0.f, m1 = 0.f;
#pragma unroll
  for (int j = 0; j < KN; ++j) {
    const int idx = __shfl(nv, j);
    const unsigned int u = h[(size_t)idx * (DD / 2) + lane];
    m0 = fmaxf(m0, __uint_as_float(u << 16));
    m1 = fmaxf(m1, __uint_as_float(u & 0xffff0000u));
  }
  float2 r;
  r.x = m0;
  r.y = m1;
  *(float2*)(out + (size_t)node * DD + lane * 2) = r;
}

extern "C" void kernel_launch(void* const* d_in, const int* in_sizes, int n_in,
                              void* d_out, int out_size, void* d_ws, size_t ws_size,
                              hipStream_t stream) {
  const float* F    = (const float*)d_in[0];  // [100000,128] f32
  const int*   nbr  = (const int*)d_in[1];    // [100000,32] i32
  const float* W    = (const float*)d_in[2];  // [128,128] f32
  const float* bias = (const float*)d_in[3];  // [128] f32
  float* out = (float*)d_out;                 // [100000,128] f32
  unsigned short* h = (unsigned short*)d_ws;  // [100000,128] bf16 (25.6 MB)

  k_transform<<<NN / 16, 256, 0, stream>>>(F, W, bias, h);
  k_gather<<<NN / 4, 256, 0, stream>>>(nbr, (const unsigned int*)h, out);
}